// Round 10
// baseline (101.467 us; speedup 1.0000x reference)
//
#include <hip/hip_runtime.h>
#include <stdint.h>

// ANFM: B=4096, F=26, V=20000, E=64, P=325 pairs.
// k1: 4 samples/block (256 thr), ONE WAVE PER SAMPLE, single barrier.
//     FUSED phase 2: MFMA scores -> max-free exp -> online-weighted acc of
//     the SAME af fragments into acf[16] (validated rounds 8-9).
//     Round-10: launch_bounds(256,5) -> 20 waves/CU (cap 102 >= live ~95);
//     scq tree reduction (4 indep partials); unmasked main loop + masked
//     tail tile; float4 W^T staging.
// k2: MLP head 64->256->128->1 (+lr+bias), 8 samples/block.
#define B_N 4096
#define F_N 26
#define V_N 20000
#define E_N 64
#define P_N 325
#define PT  21   // ceil(336/16) pair M-tiles (padded to 336 rows)

typedef __attribute__((ext_vector_type(8))) _Float16 half8;
typedef __attribute__((ext_vector_type(4))) _Float16 half4;
typedef __attribute__((ext_vector_type(4))) float floatx4;

// ---------------- attention kernel: 4 samples/block, 1 wave/sample --------
__global__ __launch_bounds__(256, 5) void anfm_attn_kernel(
    const int* __restrict__ x_idx, const float* __restrict__ embed_w,
    const float* __restrict__ embed_b, const float* __restrict__ att_w,
    const float* __restrict__ att_b, const float* __restrict__ att_p,
    float* __restrict__ ws_afm, float* __restrict__ ws_lr)
{
    __shared__ _Float16 xwb[4][F_N][72];   // fp16 gathered embeds (pad 72)
    __shared__ _Float16 WT[64][72];        // W^T fp16: WT[col][k] (pad 72)
    __shared__ unsigned short pijL[336];   // (i<<8)|j per pair
    __shared__ int   sIdx[4][F_N];
    __shared__ float lrbuf[4][F_N];
    __shared__ float apL[64], abL[64];     // attention_p / attention_b

    const int tid  = threadIdx.x;
    const int lane = tid & 63;
    const int wid  = tid >> 6;
    const int c16  = lane & 15;
    const int g    = lane >> 4;
    const int b    = blockIdx.x * 4 + wid;   // sample owned by this wave

    // ---- phase 0 (cooperative): indices, lr, pair map, W^T, ap/ab stage ----
    if (tid < 4 * F_N) {
        int s = tid / F_N, f = tid - s * F_N;
        int idx = x_idx[(blockIdx.x * 4 + s) * F_N + f];
        sIdx[s][f]  = idx;
        lrbuf[s][f] = embed_b[f * V_N + idx];
    }
    for (int p = tid; p < 336; p += 256) {
        int i = 0, j = 1;
        if (p < P_N) {
            i = (int)((51.0f - sqrtf(2601.0f - 8.0f * (float)p)) * 0.5f);
            if (i * (51 - i) / 2 > p) i--;
            else if ((i + 1) * (50 - i) / 2 <= p) i++;
            j = p - i * (51 - i) / 2 + i + 1;
        }
        pijL[p] = (unsigned short)((i << 8) | j);
    }
    if (tid < 64)        apL[tid]      = att_p[tid];
    else if (tid < 128)  abL[tid - 64] = att_b[tid - 64];
    // W^T staging via float4: thread covers att_w[k][col..col+3] -> WT[col+d][k]
    {
        const float4* aw4 = reinterpret_cast<const float4*>(att_w);
        for (int idx4 = tid; idx4 < 1024; idx4 += 256) {
            float4 v = aw4[idx4];
            int k = idx4 >> 4, col = (idx4 & 15) * 4;
            WT[col + 0][k] = (_Float16)v.x;
            WT[col + 1][k] = (_Float16)v.y;
            WT[col + 2][k] = (_Float16)v.z;
            WT[col + 3][k] = (_Float16)v.w;
        }
    }
    __syncthreads();   // the ONLY block-wide barrier

    // W fragments (rows of W^T) in registers; k-slot (g,u) <-> k = s*32+8g+u
    half8 bfr[4][2];
    #pragma unroll
    for (int nt = 0; nt < 4; nt++)
        #pragma unroll
        for (int s = 0; s < 2; s++)
            bfr[nt][s] = *reinterpret_cast<const half8*>(
                &WT[nt * 16 + c16][s * 32 + g * 8]);

    // ---- phase 1 (wave-local): gather own sample's embeddings ----
    #pragma unroll
    for (int it = 0; it < 7; it++) {
        int f = it * 4 + g;
        if (f < F_N) {
            const float4* src = reinterpret_cast<const float4*>(
                embed_w + ((size_t)(f * V_N + sIdx[wid][f])) * E_N);
            float4 v = src[c16];
            half4 hv = {(_Float16)v.x, (_Float16)v.y, (_Float16)v.z, (_Float16)v.w};
            *reinterpret_cast<half4*>(&xwb[wid][f][c16 * 4]) = hv;
        }
    }

    // ---- phase 2 (wave-local, FUSED): MFMA scores -> exp -> weighted acc ----
    // D = W^T(A) @ pairs^T(B): D col = lane&15 = pair, row = g*4+r = hidden n.
    // After the cross-g shuffles every lane holds the FULL score of pair c16
    // in this tile -> per-lane w = exp(score) weights the af fragments this
    // lane already owns (e = s*32 + 8g + u). Max-free exp: softmax is
    // shift-invariant, scores O(0.1) -> no overflow.
    float acf[16];
    #pragma unroll
    for (int u = 0; u < 16; u++) acf[u] = 0.f;
    float Zp = 0.f;

#define TILE_BODY(T, MASKED)                                                   \
    {                                                                          \
        int pk = pijL[(T) * 16 + c16];                                         \
        int ri = pk >> 8, rj = pk & 255;                                       \
        half8 af[2];                                                           \
        _Pragma("unroll")                                                      \
        for (int s = 0; s < 2; s++) {                                          \
            half8 xv = *reinterpret_cast<const half8*>(                        \
                &xwb[wid][ri][s * 32 + g * 8]);                                \
            half8 yv = *reinterpret_cast<const half8*>(                        \
                &xwb[wid][rj][s * 32 + g * 8]);                                \
            af[s] = xv * yv;                                                   \
        }                                                                      \
        float sc0, sc1, sc2, sc3;                                              \
        _Pragma("unroll")                                                      \
        for (int nt = 0; nt < 4; nt++) {                                       \
            floatx4 acc = *reinterpret_cast<const floatx4*>(                   \
                &abL[nt * 16 + g * 4]);                                        \
            acc = __builtin_amdgcn_mfma_f32_16x16x32_f16(bfr[nt][0], af[0],    \
                                                         acc, 0, 0, 0);        \
            acc = __builtin_amdgcn_mfma_f32_16x16x32_f16(bfr[nt][1], af[1],    \
                                                         acc, 0, 0, 0);        \
            floatx4 ap4 = *reinterpret_cast<const floatx4*>(                   \
                &apL[nt * 16 + g * 4]);                                        \
            float p0 = fmaf(ap4[0], fmaxf(acc[0], 0.f),                        \
                       ap4[1] * fmaxf(acc[1], 0.f));                           \
            float p1 = fmaf(ap4[2], fmaxf(acc[2], 0.f),                        \
                       ap4[3] * fmaxf(acc[3], 0.f));                           \
            float pn = p0 + p1;                                                \
            if (nt == 0) sc0 = pn; else if (nt == 1) sc1 = pn;                 \
            else if (nt == 2) sc2 = pn; else sc3 = pn;                         \
        }                                                                      \
        float scq = (sc0 + sc1) + (sc2 + sc3);                                 \
        scq += __shfl_xor(scq, 16);                                            \
        scq += __shfl_xor(scq, 32);                                            \
        float w = MASKED ? ((c16 < 5) ? __expf(scq) : 0.f) : __expf(scq);      \
        Zp += w;                                                               \
        _Pragma("unroll")                                                      \
        for (int s = 0; s < 2; s++)                                            \
            _Pragma("unroll")                                                  \
            for (int u = 0; u < 8; u++)                                        \
                acf[s * 8 + u] = fmaf((float)af[s][u], w, acf[s * 8 + u]);     \
    }

    #pragma unroll 1
    for (int t = 0; t < 20; t++)   // tiles 0..19: all 16 pairs valid
        TILE_BODY(t, 0)
    TILE_BODY(20, 1)               // tail tile: pairs 320..324 (c16 < 5)
#undef TILE_BODY

    // ---- reduce over the 16 pair-columns (c16) within each g-group ----
    #pragma unroll
    for (int msk = 1; msk <= 8; msk <<= 1) {
        Zp += __shfl_xor(Zp, msk);
        #pragma unroll
        for (int u = 0; u < 16; u++) acf[u] += __shfl_xor(acf[u], msk);
    }

    // ---- write afm (lanes c16==0: g picks the 8-element e-chunks) + lr ----
    if (c16 == 0) {
        float rZ = 1.f / Zp;
        #pragma unroll
        for (int s = 0; s < 2; s++) {
            floatx4 o0 = {acf[s * 8 + 0] * rZ, acf[s * 8 + 1] * rZ,
                          acf[s * 8 + 2] * rZ, acf[s * 8 + 3] * rZ};
            floatx4 o1 = {acf[s * 8 + 4] * rZ, acf[s * 8 + 5] * rZ,
                          acf[s * 8 + 6] * rZ, acf[s * 8 + 7] * rZ};
            *reinterpret_cast<floatx4*>(&ws_afm[(size_t)b * 64 + s * 32 + g * 8])     = o0;
            *reinterpret_cast<floatx4*>(&ws_afm[(size_t)b * 64 + s * 32 + g * 8 + 4]) = o1;
        }
    }
    float lv = (lane < F_N) ? lrbuf[wid][lane] : 0.f;
    #pragma unroll
    for (int off = 32; off; off >>= 1) lv += __shfl_xor(lv, off);
    if (lane == 0) ws_lr[b] = lv;
}

// ---------------- MLP head: 8 samples per block ----------------
__global__ __launch_bounds__(256, 4) void anfm_mlp_kernel(
    const float* __restrict__ ws_afm, const float* __restrict__ ws_lr,
    const float* __restrict__ w0, const float* __restrict__ b0,
    const float* __restrict__ w1, const float* __restrict__ b1,
    const float* __restrict__ w2, const float* __restrict__ b2,
    const float* __restrict__ bias, float* __restrict__ out)
{
    __shared__ float afm_t[8][64];
    __shared__ float h0t[8][256];
    const int tid  = threadIdx.x;
    const int lane = tid & 63;
    const int w    = tid >> 6;
    const int blk  = blockIdx.x;
    const int s0   = w * 2;    // this wave's first local sample

    for (int it = tid; it < 8 * 64; it += 256) {
        int s = it >> 6, e = it & 63;
        afm_t[s][e] = ws_afm[((size_t)blk * 8 + s) * 64 + e];
    }
    __syncthreads();

    // L0: 64 -> 256
    float acc0[2][4];
    float bb0[4];
    #pragma unroll
    for (int q = 0; q < 4; q++) bb0[q] = b0[lane + 64 * q];
    #pragma unroll
    for (int s = 0; s < 2; s++)
        #pragma unroll
        for (int q = 0; q < 4; q++) acc0[s][q] = bb0[q];
    for (int e = 0; e < 64; e += 4) {
        floatx4 a[2];
        #pragma unroll
        for (int s = 0; s < 2; s++)
            a[s] = *reinterpret_cast<const floatx4*>(&afm_t[s0 + s][e]);
        #pragma unroll
        for (int k = 0; k < 4; k++) {
            float wv[4];
            #pragma unroll
            for (int q = 0; q < 4; q++) wv[q] = w0[(e + k) * 256 + lane + 64 * q];
            #pragma unroll
            for (int s = 0; s < 2; s++)
                #pragma unroll
                for (int q = 0; q < 4; q++)
                    acc0[s][q] = fmaf(a[s][k], wv[q], acc0[s][q]);
        }
    }
    #pragma unroll
    for (int s = 0; s < 2; s++)
        #pragma unroll
        for (int q = 0; q < 4; q++)
            h0t[s0 + s][lane + 64 * q] = fmaxf(acc0[s][q], 0.f);
    __syncthreads();

    // L1: 256 -> 128
    float acc1[2][2];
    float bb1[2];
    #pragma unroll
    for (int q = 0; q < 2; q++) bb1[q] = b1[lane + 64 * q];
    #pragma unroll
    for (int s = 0; s < 2; s++)
        #pragma unroll
        for (int q = 0; q < 2; q++) acc1[s][q] = bb1[q];
    for (int e = 0; e < 256; e += 4) {
        floatx4 h[2];
        #pragma unroll
        for (int s = 0; s < 2; s++)
            h[s] = *reinterpret_cast<const floatx4*>(&h0t[s0 + s][e]);
        #pragma unroll
        for (int k = 0; k < 4; k++) {
            float wv[2];
            #pragma unroll
            for (int q = 0; q < 2; q++) wv[q] = w1[(e + k) * 128 + lane + 64 * q];
            #pragma unroll
            for (int s = 0; s < 2; s++)
                #pragma unroll
                for (int q = 0; q < 2; q++)
                    acc1[s][q] = fmaf(h[s][k], wv[q], acc1[s][q]);
        }
    }

    // L2: 128 -> 1, + lr + bias
    float w2a = w2[lane], w2b = w2[lane + 64];
    float base = b2[0] + bias[0];
    #pragma unroll
    for (int s = 0; s < 2; s++) {
        float part = fmaxf(acc1[s][0], 0.f) * w2a + fmaxf(acc1[s][1], 0.f) * w2b;
        #pragma unroll
        for (int off = 32; off; off >>= 1) part += __shfl_xor(part, off);
        if (lane == 0) {
            int sg = blk * 8 + s0 + s;
            out[sg] = part + base + ws_lr[sg];
        }
    }
}

extern "C" void kernel_launch(void* const* d_in, const int* in_sizes, int n_in,
                              void* d_out, int out_size, void* d_ws, size_t ws_size,
                              hipStream_t stream) {
    const int*   x_idx   = (const int*)d_in[0];
    const float* embed_w = (const float*)d_in[1];
    const float* embed_b = (const float*)d_in[2];
    const float* att_w   = (const float*)d_in[3];
    const float* att_b   = (const float*)d_in[4];
    const float* att_p   = (const float*)d_in[5];
    const float* w0      = (const float*)d_in[6];
    const float* b0      = (const float*)d_in[7];
    const float* w1      = (const float*)d_in[8];
    const float* b1      = (const float*)d_in[9];
    const float* w2      = (const float*)d_in[10];
    const float* b2      = (const float*)d_in[11];
    const float* bias    = (const float*)d_in[12];

    // ws layout: afm [B,64] f32 | lr [B] f32
    float* ws_afm = (float*)d_ws;
    float* ws_lr  = ws_afm + (size_t)B_N * E_N;
    float* out    = (float*)d_out;

    anfm_attn_kernel<<<B_N / 4, 256, 0, stream>>>(x_idx, embed_w, embed_b,
                                                  att_w, att_b, att_p,
                                                  ws_afm, ws_lr);
    anfm_mlp_kernel<<<B_N / 8, 256, 0, stream>>>(ws_afm, ws_lr,
                                                 w0, b0, w1, b1, w2, b2, bias, out);
}

// Round 11
// 93.528 us; speedup vs baseline: 1.0849x; 1.0849x over previous
//
#include <hip/hip_runtime.h>
#include <stdint.h>

// ANFM: B=4096, F=26, V=20000, E=64, P=325 pairs.
// k1: 4 samples/block (256 thr), ONE WAVE PER SAMPLE, single barrier.
//     FUSED phase 2 (validated r8/r9): MFMA scores -> max-free exp ->
//     online-weighted acc of the SAME af fragments into acf[16].
//     EXACT round-9 body (47.8us, clean codegen) with ONE change:
//     tile loop unroll 1 -> 2 (two independent tile chains in flight).
//     Round-10 lesson: (256,5)+macro restructure caused a 48-VGPR alloc +
//     58MB spill -- do not touch bounds or loop structure otherwise.
// k2: MLP head 64->256->128->1 (+lr+bias), 16 samples/block (halves weight
//     re-read traffic vs 8/block).
#define B_N 4096
#define F_N 26
#define V_N 20000
#define E_N 64
#define P_N 325
#define PT  21   // ceil(336/16) pair M-tiles (padded to 336 rows)

typedef __attribute__((ext_vector_type(8))) _Float16 half8;
typedef __attribute__((ext_vector_type(4))) _Float16 half4;
typedef __attribute__((ext_vector_type(4))) float floatx4;

// ---------------- attention kernel: 4 samples/block, 1 wave/sample --------
__global__ __launch_bounds__(256, 4) void anfm_attn_kernel(
    const int* __restrict__ x_idx, const float* __restrict__ embed_w,
    const float* __restrict__ embed_b, const float* __restrict__ att_w,
    const float* __restrict__ att_b, const float* __restrict__ att_p,
    float* __restrict__ ws_afm, float* __restrict__ ws_lr)
{
    __shared__ _Float16 xwb[4][F_N][72];   // fp16 gathered embeds (pad 72)
    __shared__ _Float16 WT[64][72];        // W^T fp16: WT[col][k] (pad 72)
    __shared__ unsigned short pijL[336];   // (i<<8)|j per pair
    __shared__ int   sIdx[4][F_N];
    __shared__ float lrbuf[4][F_N];
    __shared__ float apL[64], abL[64];     // attention_p / attention_b

    const int tid  = threadIdx.x;
    const int lane = tid & 63;
    const int wid  = tid >> 6;
    const int c16  = lane & 15;
    const int g    = lane >> 4;
    const int b    = blockIdx.x * 4 + wid;   // sample owned by this wave

    // ---- phase 0 (cooperative): indices, lr, pair map, W^T, ap/ab stage ----
    if (tid < 4 * F_N) {
        int s = tid / F_N, f = tid - s * F_N;
        int idx = x_idx[(blockIdx.x * 4 + s) * F_N + f];
        sIdx[s][f]  = idx;
        lrbuf[s][f] = embed_b[f * V_N + idx];
    }
    for (int p = tid; p < 336; p += 256) {
        int i = 0, j = 1;
        if (p < P_N) {
            i = (int)((51.0f - sqrtf(2601.0f - 8.0f * (float)p)) * 0.5f);
            if (i * (51 - i) / 2 > p) i--;
            else if ((i + 1) * (50 - i) / 2 <= p) i++;
            j = p - i * (51 - i) / 2 + i + 1;
        }
        pijL[p] = (unsigned short)((i << 8) | j);
    }
    if (tid < 64)                   apL[tid]      = att_p[tid];
    else if (tid < 128)             abL[tid - 64] = att_b[tid - 64];
    // W^T staging: WT[col][k] = att_w[k][col]  (coalesced f32 read)
    for (int idx = tid; idx < 64 * 64; idx += 256) {
        int k = idx >> 6, col = idx & 63;
        WT[col][k] = (_Float16)att_w[idx];
    }
    __syncthreads();   // the ONLY block-wide barrier

    // W fragments (rows of W^T) in registers; k-slot (g,u) <-> k = s*32+8g+u
    half8 bfr[4][2];
    #pragma unroll
    for (int nt = 0; nt < 4; nt++)
        #pragma unroll
        for (int s = 0; s < 2; s++)
            bfr[nt][s] = *reinterpret_cast<const half8*>(
                &WT[nt * 16 + c16][s * 32 + g * 8]);

    // ---- phase 1 (wave-local): gather own sample's embeddings ----
    #pragma unroll
    for (int it = 0; it < 7; it++) {
        int f = it * 4 + g;
        if (f < F_N) {
            const float4* src = reinterpret_cast<const float4*>(
                embed_w + ((size_t)(f * V_N + sIdx[wid][f])) * E_N);
            float4 v = src[c16];
            half4 hv = {(_Float16)v.x, (_Float16)v.y, (_Float16)v.z, (_Float16)v.w};
            *reinterpret_cast<half4*>(&xwb[wid][f][c16 * 4]) = hv;
        }
    }

    // ---- phase 2 (wave-local, FUSED): MFMA scores -> exp -> weighted acc ----
    // D = W^T(A) @ pairs^T(B): D col = lane&15 = pair, row = g*4+r = hidden n.
    // After the cross-g shuffles every lane holds the FULL score of pair c16
    // in this tile -> per-lane w = exp(score) weights the af fragments this
    // lane already owns (e = s*32 + 8g + u). Max-free exp: softmax is
    // shift-invariant and scores are O(0.1) -> no overflow. ab via the MFMA
    // C operand (LDS broadcast), ap via LDS broadcast -> no apr/abr arrays.
    float acf[16];
    #pragma unroll
    for (int u = 0; u < 16; u++) acf[u] = 0.f;
    float Zp = 0.f;

    #pragma unroll 2
    for (int t = 0; t < PT; t++) {
        int pk = pijL[t * 16 + c16];
        int ri = pk >> 8, rj = pk & 255;
        half8 af[2];
        #pragma unroll
        for (int s = 0; s < 2; s++) {
            half8 xv = *reinterpret_cast<const half8*>(&xwb[wid][ri][s * 32 + g * 8]);
            half8 yv = *reinterpret_cast<const half8*>(&xwb[wid][rj][s * 32 + g * 8]);
            af[s] = xv * yv;   // 4x v_pk_mul_f16
        }
        float scq = 0.f;
        #pragma unroll
        for (int nt = 0; nt < 4; nt++) {
            floatx4 acc = *reinterpret_cast<const floatx4*>(&abL[nt * 16 + g * 4]);
            acc = __builtin_amdgcn_mfma_f32_16x16x32_f16(bfr[nt][0], af[0], acc, 0, 0, 0);
            acc = __builtin_amdgcn_mfma_f32_16x16x32_f16(bfr[nt][1], af[1], acc, 0, 0, 0);
            floatx4 ap4 = *reinterpret_cast<const floatx4*>(&apL[nt * 16 + g * 4]);
            #pragma unroll
            for (int r = 0; r < 4; r++)
                scq = fmaf(ap4[r], fmaxf(acc[r], 0.f), scq);
        }
        scq += __shfl_xor(scq, 16);   // reduce over g groups (hidden chunks)
        scq += __shfl_xor(scq, 32);
        float w = (t * 16 + c16 < P_N) ? __expf(scq) : 0.f;
        Zp += w;
        #pragma unroll
        for (int s = 0; s < 2; s++)
            #pragma unroll
            for (int u = 0; u < 8; u++)
                acf[s * 8 + u] = fmaf((float)af[s][u], w, acf[s * 8 + u]);  // fma_mix
    }

    // ---- reduce over the 16 pair-columns (c16) within each g-group ----
    #pragma unroll
    for (int msk = 1; msk <= 8; msk <<= 1) {
        Zp += __shfl_xor(Zp, msk);
        #pragma unroll
        for (int u = 0; u < 16; u++) acf[u] += __shfl_xor(acf[u], msk);
    }

    // ---- write afm (lanes c16==0: g picks the 8-element e-chunks) + lr ----
    if (c16 == 0) {
        float rZ = 1.f / Zp;
        #pragma unroll
        for (int s = 0; s < 2; s++) {
            floatx4 o0 = {acf[s * 8 + 0] * rZ, acf[s * 8 + 1] * rZ,
                          acf[s * 8 + 2] * rZ, acf[s * 8 + 3] * rZ};
            floatx4 o1 = {acf[s * 8 + 4] * rZ, acf[s * 8 + 5] * rZ,
                          acf[s * 8 + 6] * rZ, acf[s * 8 + 7] * rZ};
            *reinterpret_cast<floatx4*>(&ws_afm[(size_t)b * 64 + s * 32 + g * 8])     = o0;
            *reinterpret_cast<floatx4*>(&ws_afm[(size_t)b * 64 + s * 32 + g * 8 + 4]) = o1;
        }
    }
    float lv = (lane < F_N) ? lrbuf[wid][lane] : 0.f;
    #pragma unroll
    for (int off = 32; off; off >>= 1) lv += __shfl_xor(lv, off);
    if (lane == 0) ws_lr[b] = lv;
}

// ---------------- MLP head: 16 samples per block ----------------
__global__ __launch_bounds__(256, 4) void anfm_mlp_kernel(
    const float* __restrict__ ws_afm, const float* __restrict__ ws_lr,
    const float* __restrict__ w0, const float* __restrict__ b0,
    const float* __restrict__ w1, const float* __restrict__ b1,
    const float* __restrict__ w2, const float* __restrict__ b2,
    const float* __restrict__ bias, float* __restrict__ out)
{
    __shared__ float afm_t[16][64];
    __shared__ float h0t[16][256];
    const int tid  = threadIdx.x;
    const int lane = tid & 63;
    const int w    = tid >> 6;
    const int blk  = blockIdx.x;
    const int s0   = w * 4;    // this wave's first local sample

    for (int it = tid; it < 16 * 64; it += 256) {
        int s = it >> 6, e = it & 63;
        afm_t[s][e] = ws_afm[((size_t)blk * 16 + s) * 64 + e];
    }
    __syncthreads();

    // L0: 64 -> 256
    float acc0[4][4];
    float bb0[4];
    #pragma unroll
    for (int q = 0; q < 4; q++) bb0[q] = b0[lane + 64 * q];
    #pragma unroll
    for (int s = 0; s < 4; s++)
        #pragma unroll
        for (int q = 0; q < 4; q++) acc0[s][q] = bb0[q];
    for (int e = 0; e < 64; e += 4) {
        floatx4 a[4];
        #pragma unroll
        for (int s = 0; s < 4; s++)
            a[s] = *reinterpret_cast<const floatx4*>(&afm_t[s0 + s][e]);
        #pragma unroll
        for (int k = 0; k < 4; k++) {
            float wv[4];
            #pragma unroll
            for (int q = 0; q < 4; q++) wv[q] = w0[(e + k) * 256 + lane + 64 * q];
            #pragma unroll
            for (int s = 0; s < 4; s++)
                #pragma unroll
                for (int q = 0; q < 4; q++)
                    acc0[s][q] = fmaf(a[s][k], wv[q], acc0[s][q]);
        }
    }
    #pragma unroll
    for (int s = 0; s < 4; s++)
        #pragma unroll
        for (int q = 0; q < 4; q++)
            h0t[s0 + s][lane + 64 * q] = fmaxf(acc0[s][q], 0.f);
    __syncthreads();

    // L1: 256 -> 128
    float acc1[4][2];
    float bb1[2];
    #pragma unroll
    for (int q = 0; q < 2; q++) bb1[q] = b1[lane + 64 * q];
    #pragma unroll
    for (int s = 0; s < 4; s++)
        #pragma unroll
        for (int q = 0; q < 2; q++) acc1[s][q] = bb1[q];
    for (int e = 0; e < 256; e += 4) {
        floatx4 h[4];
        #pragma unroll
        for (int s = 0; s < 4; s++)
            h[s] = *reinterpret_cast<const floatx4*>(&h0t[s0 + s][e]);
        #pragma unroll
        for (int k = 0; k < 4; k++) {
            float wv[2];
            #pragma unroll
            for (int q = 0; q < 2; q++) wv[q] = w1[(e + k) * 128 + lane + 64 * q];
            #pragma unroll
            for (int s = 0; s < 4; s++)
                #pragma unroll
                for (int q = 0; q < 2; q++)
                    acc1[s][q] = fmaf(h[s][k], wv[q], acc1[s][q]);
        }
    }

    // L2: 128 -> 1, + lr + bias
    float w2a = w2[lane], w2b = w2[lane + 64];
    float base = b2[0] + bias[0];
    #pragma unroll
    for (int s = 0; s < 4; s++) {
        float part = fmaxf(acc1[s][0], 0.f) * w2a + fmaxf(acc1[s][1], 0.f) * w2b;
        #pragma unroll
        for (int off = 32; off; off >>= 1) part += __shfl_xor(part, off);
        if (lane == 0) {
            int sg = blk * 16 + s0 + s;
            out[sg] = part + base + ws_lr[sg];
        }
    }
}

extern "C" void kernel_launch(void* const* d_in, const int* in_sizes, int n_in,
                              void* d_out, int out_size, void* d_ws, size_t ws_size,
                              hipStream_t stream) {
    const int*   x_idx   = (const int*)d_in[0];
    const float* embed_w = (const float*)d_in[1];
    const float* embed_b = (const float*)d_in[2];
    const float* att_w   = (const float*)d_in[3];
    const float* att_b   = (const float*)d_in[4];
    const float* att_p   = (const float*)d_in[5];
    const float* w0      = (const float*)d_in[6];
    const float* b0      = (const float*)d_in[7];
    const float* w1      = (const float*)d_in[8];
    const float* b1      = (const float*)d_in[9];
    const float* w2      = (const float*)d_in[10];
    const float* b2      = (const float*)d_in[11];
    const float* bias    = (const float*)d_in[12];

    // ws layout: afm [B,64] f32 | lr [B] f32
    float* ws_afm = (float*)d_ws;
    float* ws_lr  = ws_afm + (size_t)B_N * E_N;
    float* out    = (float*)d_out;

    anfm_attn_kernel<<<B_N / 4, 256, 0, stream>>>(x_idx, embed_w, embed_b,
                                                  att_w, att_b, att_p,
                                                  ws_afm, ws_lr);
    anfm_mlp_kernel<<<B_N / 16, 256, 0, stream>>>(ws_afm, ws_lr,
                                                  w0, b0, w1, b1, w2, b2, bias, out);
}

// Round 12
// 41.799 us; speedup vs baseline: 2.4275x; 2.2376x over previous
//
#include <hip/hip_runtime.h>
#include <stdint.h>

// ANFM: B=4096, F=26, V=20000, E=64, P=325 pairs.
// k1: EXACT round-9 attention kernel (proven clean codegen, no spill):
//     4 samples/block, 1 wave/sample, fused MFMA->exp->online-weighted acc,
//     unroll 1, launch_bounds(256,4). DO NOT widen the tile loop or bounds:
//     rounds 8/10/11 all spilled (VGPR 48-64, WRITE_SIZE 58-166MB).
// k2: NEW MFMA MLP head: 16 samples/block = one 16-row M-tile.
//     L0: D[16,256]=afm@w0 (8 MFMA/wave), L1: D[16,128]=h0@w1 (16 MFMA/wave),
//     B-frags gathered from L2-hot w0/w1; h0 fp16 LDS, h1 f32 LDS; final
//     dot(h1,w2)+b2+bias+lr epilogue. Replaces ~2.5k VALU/thread with ~24
//     MFMA/wave -- the VALU mlp was a hidden ~15us latency-bound constant.
#define B_N 4096
#define F_N 26
#define V_N 20000
#define E_N 64
#define P_N 325
#define PT  21   // ceil(336/16) pair M-tiles (padded to 336 rows)

typedef __attribute__((ext_vector_type(8))) _Float16 half8;
typedef __attribute__((ext_vector_type(4))) _Float16 half4;
typedef __attribute__((ext_vector_type(4))) float floatx4;

// ---------------- attention kernel: 4 samples/block, 1 wave/sample --------
__global__ __launch_bounds__(256, 4) void anfm_attn_kernel(
    const int* __restrict__ x_idx, const float* __restrict__ embed_w,
    const float* __restrict__ embed_b, const float* __restrict__ att_w,
    const float* __restrict__ att_b, const float* __restrict__ att_p,
    float* __restrict__ ws_afm, float* __restrict__ ws_lr)
{
    __shared__ _Float16 xwb[4][F_N][72];   // fp16 gathered embeds (pad 72)
    __shared__ _Float16 WT[64][72];        // W^T fp16: WT[col][k] (pad 72)
    __shared__ unsigned short pijL[336];   // (i<<8)|j per pair
    __shared__ int   sIdx[4][F_N];
    __shared__ float lrbuf[4][F_N];
    __shared__ float apL[64], abL[64];     // attention_p / attention_b

    const int tid  = threadIdx.x;
    const int lane = tid & 63;
    const int wid  = tid >> 6;
    const int c16  = lane & 15;
    const int g    = lane >> 4;
    const int b    = blockIdx.x * 4 + wid;   // sample owned by this wave

    // ---- phase 0 (cooperative): indices, lr, pair map, W^T, ap/ab stage ----
    if (tid < 4 * F_N) {
        int s = tid / F_N, f = tid - s * F_N;
        int idx = x_idx[(blockIdx.x * 4 + s) * F_N + f];
        sIdx[s][f]  = idx;
        lrbuf[s][f] = embed_b[f * V_N + idx];
    }
    for (int p = tid; p < 336; p += 256) {
        int i = 0, j = 1;
        if (p < P_N) {
            i = (int)((51.0f - sqrtf(2601.0f - 8.0f * (float)p)) * 0.5f);
            if (i * (51 - i) / 2 > p) i--;
            else if ((i + 1) * (50 - i) / 2 <= p) i++;
            j = p - i * (51 - i) / 2 + i + 1;
        }
        pijL[p] = (unsigned short)((i << 8) | j);
    }
    if (tid < 64)                   apL[tid]      = att_p[tid];
    else if (tid < 128)             abL[tid - 64] = att_b[tid - 64];
    // W^T staging: WT[col][k] = att_w[k][col]  (coalesced f32 read)
    for (int idx = tid; idx < 64 * 64; idx += 256) {
        int k = idx >> 6, col = idx & 63;
        WT[col][k] = (_Float16)att_w[idx];
    }
    __syncthreads();   // the ONLY block-wide barrier

    // W fragments (rows of W^T) in registers; k-slot (g,u) <-> k = s*32+8g+u
    half8 bfr[4][2];
    #pragma unroll
    for (int nt = 0; nt < 4; nt++)
        #pragma unroll
        for (int s = 0; s < 2; s++)
            bfr[nt][s] = *reinterpret_cast<const half8*>(
                &WT[nt * 16 + c16][s * 32 + g * 8]);

    // ---- phase 1 (wave-local): gather own sample's embeddings ----
    #pragma unroll
    for (int it = 0; it < 7; it++) {
        int f = it * 4 + g;
        if (f < F_N) {
            const float4* src = reinterpret_cast<const float4*>(
                embed_w + ((size_t)(f * V_N + sIdx[wid][f])) * E_N);
            float4 v = src[c16];
            half4 hv = {(_Float16)v.x, (_Float16)v.y, (_Float16)v.z, (_Float16)v.w};
            *reinterpret_cast<half4*>(&xwb[wid][f][c16 * 4]) = hv;
        }
    }

    // ---- phase 2 (wave-local, FUSED): MFMA scores -> exp -> weighted acc ----
    // D = W^T(A) @ pairs^T(B): D col = lane&15 = pair, row = g*4+r = hidden n.
    // After the cross-g shuffles every lane holds the FULL score of pair c16
    // in this tile -> per-lane w = exp(score) weights the af fragments this
    // lane already owns (e = s*32 + 8g + u). Max-free exp: softmax is
    // shift-invariant and scores are O(0.1) -> no overflow.
    float acf[16];
    #pragma unroll
    for (int u = 0; u < 16; u++) acf[u] = 0.f;
    float Zp = 0.f;

    #pragma unroll 1
    for (int t = 0; t < PT; t++) {
        int pk = pijL[t * 16 + c16];
        int ri = pk >> 8, rj = pk & 255;
        half8 af[2];
        #pragma unroll
        for (int s = 0; s < 2; s++) {
            half8 xv = *reinterpret_cast<const half8*>(&xwb[wid][ri][s * 32 + g * 8]);
            half8 yv = *reinterpret_cast<const half8*>(&xwb[wid][rj][s * 32 + g * 8]);
            af[s] = xv * yv;   // 4x v_pk_mul_f16
        }
        float scq = 0.f;
        #pragma unroll
        for (int nt = 0; nt < 4; nt++) {
            floatx4 acc = *reinterpret_cast<const floatx4*>(&abL[nt * 16 + g * 4]);
            acc = __builtin_amdgcn_mfma_f32_16x16x32_f16(bfr[nt][0], af[0], acc, 0, 0, 0);
            acc = __builtin_amdgcn_mfma_f32_16x16x32_f16(bfr[nt][1], af[1], acc, 0, 0, 0);
            floatx4 ap4 = *reinterpret_cast<const floatx4*>(&apL[nt * 16 + g * 4]);
            #pragma unroll
            for (int r = 0; r < 4; r++)
                scq = fmaf(ap4[r], fmaxf(acc[r], 0.f), scq);
        }
        scq += __shfl_xor(scq, 16);   // reduce over g groups (hidden chunks)
        scq += __shfl_xor(scq, 32);
        float w = (t * 16 + c16 < P_N) ? __expf(scq) : 0.f;
        Zp += w;
        #pragma unroll
        for (int s = 0; s < 2; s++)
            #pragma unroll
            for (int u = 0; u < 8; u++)
                acf[s * 8 + u] = fmaf((float)af[s][u], w, acf[s * 8 + u]);  // fma_mix
    }

    // ---- reduce over the 16 pair-columns (c16) within each g-group ----
    #pragma unroll
    for (int msk = 1; msk <= 8; msk <<= 1) {
        Zp += __shfl_xor(Zp, msk);
        #pragma unroll
        for (int u = 0; u < 16; u++) acf[u] += __shfl_xor(acf[u], msk);
    }

    // ---- write afm (lanes c16==0: g picks the 8-element e-chunks) + lr ----
    if (c16 == 0) {
        float rZ = 1.f / Zp;
        #pragma unroll
        for (int s = 0; s < 2; s++) {
            floatx4 o0 = {acf[s * 8 + 0] * rZ, acf[s * 8 + 1] * rZ,
                          acf[s * 8 + 2] * rZ, acf[s * 8 + 3] * rZ};
            floatx4 o1 = {acf[s * 8 + 4] * rZ, acf[s * 8 + 5] * rZ,
                          acf[s * 8 + 6] * rZ, acf[s * 8 + 7] * rZ};
            *reinterpret_cast<floatx4*>(&ws_afm[(size_t)b * 64 + s * 32 + g * 8])     = o0;
            *reinterpret_cast<floatx4*>(&ws_afm[(size_t)b * 64 + s * 32 + g * 8 + 4]) = o1;
        }
    }
    float lv = (lane < F_N) ? lrbuf[wid][lane] : 0.f;
    #pragma unroll
    for (int off = 32; off; off >>= 1) lv += __shfl_xor(lv, off);
    if (lane == 0) ws_lr[b] = lv;
}

// ---------------- MFMA MLP head: 16 samples per block (one M-tile) -------
// Same verified MFMA convention as attn: mfma(A,B) -> D row = A-lane index
// (g*4+r), D col = B-lane index (c16); k-slot (g,u) <-> k = base + 8g + u,
// identical for A and B fragments.
__global__ __launch_bounds__(256, 4) void anfm_mlp_kernel(
    const float* __restrict__ ws_afm, const float* __restrict__ ws_lr,
    const float* __restrict__ w0, const float* __restrict__ b0,
    const float* __restrict__ w1, const float* __restrict__ b1,
    const float* __restrict__ w2, const float* __restrict__ b2,
    const float* __restrict__ bias, float* __restrict__ out)
{
    __shared__ _Float16 afmL[16][72];    // A for L0 (fp16, pad 72)
    __shared__ _Float16 h0L[16][264];    // relu(L0) fp16, K=256 (pad 264)
    __shared__ float    h1L[16][132];    // relu-input of L2 (f32, pad 132)

    const int tid  = threadIdx.x;
    const int lane = tid & 63;
    const int wid  = tid >> 6;
    const int c16  = lane & 15;
    const int g    = lane >> 4;
    const int blk  = blockIdx.x;

    // stage afm -> fp16 LDS (A rows = samples)
    for (int it = tid; it < 16 * 64; it += 256) {
        int s = it >> 6, e = it & 63;
        afmL[s][e] = (_Float16)ws_afm[((size_t)blk * 16 + s) * 64 + e];
    }
    __syncthreads();

    // ---- L0: D[16,256] = afm[16,64] @ w0[64,256] + b0, relu -> h0L ----
    // wave wid covers n-tiles nt = wid*4 .. wid*4+3
    {
        half8 af[2];
        #pragma unroll
        for (int s = 0; s < 2; s++)
            af[s] = *reinterpret_cast<const half8*>(&afmL[c16][s * 32 + g * 8]);
        #pragma unroll
        for (int q = 0; q < 4; q++) {
            int n = (wid * 4 + q) * 16 + c16;
            half8 bf[2];
            #pragma unroll
            for (int s = 0; s < 2; s++)
                #pragma unroll
                for (int u = 0; u < 8; u++)
                    bf[s][u] = (_Float16)w0[(s * 32 + g * 8 + u) * 256 + n];
            floatx4 acc = {0.f, 0.f, 0.f, 0.f};
            acc = __builtin_amdgcn_mfma_f32_16x16x32_f16(af[0], bf[0], acc, 0, 0, 0);
            acc = __builtin_amdgcn_mfma_f32_16x16x32_f16(af[1], bf[1], acc, 0, 0, 0);
            float b0n = b0[n];
            #pragma unroll
            for (int r = 0; r < 4; r++)
                h0L[g * 4 + r][n] = (_Float16)fmaxf(acc[r] + b0n, 0.f);
        }
    }
    __syncthreads();

    // ---- L1: D[16,128] = h0[16,256] @ w1[256,128] + b1, relu -> h1L ----
    // wave wid covers n-tiles nt = wid*2, wid*2+1
    #pragma unroll
    for (int q = 0; q < 2; q++) {
        int n = (wid * 2 + q) * 16 + c16;
        floatx4 acc = {0.f, 0.f, 0.f, 0.f};
        #pragma unroll
        for (int ks = 0; ks < 8; ks++) {
            half8 af = *reinterpret_cast<const half8*>(&h0L[c16][ks * 32 + g * 8]);
            half8 bf;
            #pragma unroll
            for (int u = 0; u < 8; u++)
                bf[u] = (_Float16)w1[(ks * 32 + g * 8 + u) * 128 + n];
            acc = __builtin_amdgcn_mfma_f32_16x16x32_f16(af, bf, acc, 0, 0, 0);
        }
        float b1n = b1[n];
        #pragma unroll
        for (int r = 0; r < 4; r++)
            h1L[g * 4 + r][n] = fmaxf(acc[r] + b1n, 0.f);
    }
    __syncthreads();

    // ---- L2: out = h1 @ w2 + b2 + bias + lr ----
    float w2a = w2[lane * 2], w2b = w2[lane * 2 + 1];
    float base = b2[0] + bias[0];
    #pragma unroll
    for (int s = 0; s < 4; s++) {
        int m = wid * 4 + s;
        float part = fmaf(h1L[m][lane * 2], w2a, h1L[m][lane * 2 + 1] * w2b);
        #pragma unroll
        for (int off = 32; off; off >>= 1) part += __shfl_xor(part, off);
        if (lane == 0) {
            int sg = blk * 16 + m;
            out[sg] = part + base + ws_lr[sg];
        }
    }
}

extern "C" void kernel_launch(void* const* d_in, const int* in_sizes, int n_in,
                              void* d_out, int out_size, void* d_ws, size_t ws_size,
                              hipStream_t stream) {
    const int*   x_idx   = (const int*)d_in[0];
    const float* embed_w = (const float*)d_in[1];
    const float* embed_b = (const float*)d_in[2];
    const float* att_w   = (const float*)d_in[3];
    const float* att_b   = (const float*)d_in[4];
    const float* att_p   = (const float*)d_in[5];
    const float* w0      = (const float*)d_in[6];
    const float* b0      = (const float*)d_in[7];
    const float* w1      = (const float*)d_in[8];
    const float* b1      = (const float*)d_in[9];
    const float* w2      = (const float*)d_in[10];
    const float* b2      = (const float*)d_in[11];
    const float* bias    = (const float*)d_in[12];

    // ws layout: afm [B,64] f32 | lr [B] f32
    float* ws_afm = (float*)d_ws;
    float* ws_lr  = ws_afm + (size_t)B_N * E_N;
    float* out    = (float*)d_out;

    anfm_attn_kernel<<<B_N / 4, 256, 0, stream>>>(x_idx, embed_w, embed_b,
                                                  att_w, att_b, att_p,
                                                  ws_afm, ws_lr);
    anfm_mlp_kernel<<<B_N / 16, 256, 0, stream>>>(ws_afm, ws_lr,
                                                  w0, b0, w1, b1, w2, b2, bias, out);
}